// Round 5
// baseline (291.876 us; speedup 1.0000x reference)
//
#include <hip/hip_runtime.h>

#define NN 50000
#define NE 800000
#define EPSV 1e-5f
#define NBIN 196    // ceil(NE / 4096) position bins
#define CHUNK 2048  // edges per k_binA block

typedef unsigned int u32;
typedef short s16x8 __attribute__((ext_vector_type(8)));
typedef float f32x4 __attribute__((ext_vector_type(4)));

// ws: aggxb/yb [NN*64 f] | xb [NN*32] | st [1024] | deg [NN] | cur [NN] | csr [NE]
//     | psum/pssq [2*400000] (rank aliases) | recs [802816 uint2]
#define WS_NEEDED \
  ((size_t)(NN * 64 + NN * 32 + 1024 + NN + NN + NE + 2 * 400000 + 2 * 802816) * 4)

__global__ void k_fallback(float* __restrict__ out) {
  int i = blockIdx.x * 256 + threadIdx.x;
  if (i < NN * 128) out[i] = 2.0f;
}

// mode: 1 = int64 (odd 32-bit words of first 32 values all zero), 0 = int32.
// Also zeroes binCur (196 ints) for k_binA.
__global__ void k_detect(const int* __restrict__ ei, int* __restrict__ mode,
                         int* __restrict__ binCur) {
  for (int i = threadIdx.x; i < NBIN; i += 64) binCur[i] = 0;
  if (threadIdx.x == 0) {
    int all0 = 1;
    for (int i = 1; i < 64; i += 2) all0 &= (ei[i] == 0);
    *mode = all0;
  }
}

__device__ __forceinline__ void load_edge(const int* __restrict__ ei, int m, int e,
                                          int& src, int& dst) {
  if (m) { src = ei[e << 1]; dst = ei[(NE + e) << 1]; }
  else   { src = ei[e];      dst = ei[NE + e]; }
  src = min(max(src, 0), NN - 1);
  dst = min(max(dst, 0), NN - 1);
}

// rank trick: rank[e] = per-dst arrival order; placement then needs no atomic.
__global__ __launch_bounds__(256) void k_hist(
    const int* __restrict__ ei, const int* __restrict__ mode,
    int* __restrict__ deg, int* __restrict__ rank) {
  int e = blockIdx.x * 256 + threadIdx.x;
  int src, dst;
  load_edge(ei, *mode, e, src, dst);
  rank[e] = atomicAdd(&deg[dst], 1);
}

// Stage 1: per-256-chunk sums of deg. 196 blocks.
__global__ __launch_bounds__(256) void k_scan1(
    const int* __restrict__ deg, int* __restrict__ bsum) {
  const int b = blockIdx.x, t = threadIdx.x;
  const int lane = t & 63, wave = t >> 6;
  int idx = b * 256 + t;
  int v = (idx < NN) ? deg[idx] : 0;
  for (int off = 32; off > 0; off >>= 1) v += __shfl_down(v, off);
  __shared__ int wt[4];
  if (lane == 0) wt[wave] = v;
  __syncthreads();
  if (t == 0) bsum[b] = wt[0] + wt[1] + wt[2] + wt[3];
}

// Stage 2: block offset = reduce(bsum[0..b)), then block-wide exclusive scan.
__global__ __launch_bounds__(256) void k_scan3(
    const int* __restrict__ deg, const int* __restrict__ bsum, int* __restrict__ cur) {
  const int b = blockIdx.x, t = threadIdx.x;
  const int lane = t & 63, wave = t >> 6;
  __shared__ int wt[4];
  __shared__ int boff;
  int pv = (t < b) ? bsum[t] : 0;  // b <= 195 < 256
  int r = pv;
  for (int off = 32; off > 0; off >>= 1) r += __shfl_down(r, off);
  if (lane == 0) wt[wave] = r;
  __syncthreads();
  if (t == 0) boff = wt[0] + wt[1] + wt[2] + wt[3];
  __syncthreads();
  int idx = b * 256 + t;
  int v = (idx < NN) ? deg[idx] : 0;
  int incl = v;
  for (int off = 1; off < 64; off <<= 1) {
    int u = __shfl_up(incl, off);
    if (lane >= off) incl += u;
  }
  if (lane == 63) wt[wave] = incl;
  __syncthreads();
  int woff = 0;
  for (int w = 0; w < wave; ++w) woff += wt[w];
  if (idx < NN) cur[idx] = boff + woff + incl - v;  // exclusive start offsets
}

// Pass A of binned CSR build: compute pos = cur[dst]+rank[e], partition records
// (src,pos) into 196 position-bins (bin = pos>>12, fixed 4096-slot capacity).
// LDS reorder -> coalesced per-bin runs (kills the 16x scatter amplification).
__global__ __launch_bounds__(256) void k_binA(
    const int* __restrict__ ei, const int* __restrict__ mode,
    const int* __restrict__ cur, const int* __restrict__ rank,
    uint2* __restrict__ recs, int* __restrict__ binCur) {
  __shared__ int hist[256];
  __shared__ int lofs[256];
  __shared__ int gofs[256];
  __shared__ int wtot[4];
  __shared__ uint2 buf[CHUNK];
  const int t = threadIdx.x;
  const int eb = blockIdx.x * CHUNK;
  const int tot = min(CHUNK, NE - eb);
  hist[t] = 0;
  __syncthreads();
  const int m = *mode;
  int pos[CHUNK / 256], srcv[CHUNK / 256];
#pragma unroll
  for (int it = 0; it < CHUNK / 256; ++it) {
    int e = eb + it * 256 + t;
    if (e < NE) {
      int s, d;
      load_edge(ei, m, e, s, d);
      int p = cur[d] + rank[e];
      pos[it] = p;
      srcv[it] = s;
      atomicAdd(&hist[p >> 12], 1);
    } else {
      pos[it] = -1;
    }
  }
  __syncthreads();
  // exclusive block scan of hist -> lofs; reserve global per-bin ranges
  int v = hist[t];
  const int lane = t & 63, wv = t >> 6;
  int incl = v;
  for (int off = 1; off < 64; off <<= 1) {
    int u = __shfl_up(incl, off);
    if (lane >= off) incl += u;
  }
  if (lane == 63) wtot[wv] = incl;
  __syncthreads();
  int woff = 0;
  for (int w = 0; w < wv; ++w) woff += wtot[w];
  lofs[t] = woff + incl - v;
  if (v > 0) gofs[t] = atomicAdd(&binCur[t], v);
  __syncthreads();
  hist[t] = 0;
  __syncthreads();
#pragma unroll
  for (int it = 0; it < CHUNK / 256; ++it) {
    if (pos[it] >= 0) {
      int b = pos[it] >> 12;
      int o = atomicAdd(&hist[b], 1);
      buf[lofs[b] + o] = make_uint2((u32)srcv[it], (u32)pos[it]);
    }
  }
  __syncthreads();
  for (int j = t; j < tot; j += 256) {
    uint2 r = buf[j];
    int b = (int)(r.y >> 12);
    recs[(size_t)b * 4096 + gofs[b] + (j - lofs[b])] = r;
  }
}

// Pass B: per bin, scatter within a 16KB csr window -> L2-resident, full-line
// writeback (HBM write = 3.2MB instead of 51MB).
__global__ __launch_bounds__(256) void k_binB(
    const uint2* __restrict__ recs, const int* __restrict__ binCur,
    int* __restrict__ csr) {
  const int b = blockIdx.x;
  const int cnt = binCur[b];
  const uint2* r = &recs[(size_t)b * 4096];
  for (int j = threadIdx.x; j < cnt; j += 256) {
    uint2 q = r[j];
    csr[q.y] = (int)q.x;
  }
}

__device__ __forceinline__ u32 pack_bf16(float lo, float hi) {
  union { float f; u32 u; } a, b;
  a.f = lo; b.f = hi;
  u32 ua = a.u + 0x7fffu + ((a.u >> 16) & 1u);
  u32 ub = b.u + 0x7fffu + ((b.u >> 16) & 1u);
  return (ua >> 16) | (ub & 0xffff0000u);
}
#define BFLO(u) __uint_as_float((u) << 16)
#define BFHI(u) __uint_as_float((u) & 0xffff0000u)

// xb[n*32+c] = pack(x[n*64+2c], x[n*64+2c+1])
__global__ __launch_bounds__(256) void k_pack(
    const float* __restrict__ x, u32* __restrict__ xb) {
  int i = blockIdx.x * 256 + threadIdx.x;  // over NN*32
  int n = i >> 5, c = i & 31;
  float2 v = *(const float2*)&x[n * 64 + c * 2];
  xb[i] = pack_bf16(v.x, v.y);
}

// aggxb[n*32+2L..2L+1] = packed-bf16 sums over incoming edges of xb[src].
// 16 lanes/node, uint2/lane. bf16 output: identical rounding to what k_gemm_a
// staging did before, but halves aggx traffic (12.8 -> 6.4 MB each way).
__global__ __launch_bounds__(256) void k_gather_xb(
    const u32* __restrict__ xb, const int* __restrict__ csr,
    const int* __restrict__ cur, const int* __restrict__ deg,
    u32* __restrict__ aggxb) {
  int tid = blockIdx.x * 256 + threadIdx.x;
  int n = tid >> 4, L = tid & 15;
  int i = cur[n];
  int end = i + deg[n];
  float a0 = 0.f, a1 = 0.f, a2 = 0.f, a3 = 0.f;
  float b0 = 0.f, b1 = 0.f, b2 = 0.f, b3 = 0.f;
  for (; i + 1 < end; i += 2) {
    int s0 = csr[i], s1 = csr[i + 1];
    uint2 u = *(const uint2*)&xb[s0 * 32 + 2 * L];
    uint2 w = *(const uint2*)&xb[s1 * 32 + 2 * L];
    a0 += BFLO(u.x); a1 += BFHI(u.x); a2 += BFLO(u.y); a3 += BFHI(u.y);
    b0 += BFLO(w.x); b1 += BFHI(w.x); b2 += BFLO(w.y); b3 += BFHI(w.y);
  }
  if (i < end) {
    int s0 = csr[i];
    uint2 u = *(const uint2*)&xb[s0 * 32 + 2 * L];
    a0 += BFLO(u.x); a1 += BFHI(u.x); a2 += BFLO(u.y); a3 += BFHI(u.y);
  }
  uint2 o;
  o.x = pack_bf16(a0 + b0, a1 + b1);
  o.y = pack_bf16(a2 + b2, a3 + b3);
  *(uint2*)&aggxb[n * 32 + 2 * L] = o;
}

// Pre-pack [Wrel0 ; Wroot0] (stacked K=128, N=128) into bf16 MFMA B-fragment
// order. 8192 u32 = 32 KB.
__global__ __launch_bounds__(256) void k_packW0(
    const float* __restrict__ Wrel, const float* __restrict__ Wroot,
    u32* __restrict__ Wpk0) {
  int t = blockIdx.x * 256 + threadIdx.x;  // 0..8191
  int r = t & 3, lane = (t >> 2) & 63, s = (t >> 8) & 3, nt = t >> 10;
  int k = 32 * s + (lane >> 4) * 8 + 2 * r;
  int col = 16 * nt + (lane & 15);
  const float* W = (k < 64) ? &Wrel[k * 128 + col] : &Wroot[(k - 64) * 128 + col];
  Wpk0[t] = pack_bf16(W[0], W[128]);
}

// h = [aggx | x] @ [Wrel0 ; Wroot0] (M=NN, K=128, N=128) + fused BN0 partials.
// MFMA bf16: 128-node tile, 4 waves, wave w owns cols [32w, 32w+32).
// A staged in 32KB XOR-swizzled LDS; aggx half copied pre-packed from aggxb.
__global__ __launch_bounds__(256) void k_gemm_a(
    const float* __restrict__ x, const u32* __restrict__ aggxb,
    const u32* __restrict__ Wpk0,
    float* __restrict__ h, float* __restrict__ psum, float* __restrict__ pssq) {
  __shared__ u32 As[8192];  // 128 rows x 128 k bf16, XOR-swizzled
  const int tid = threadIdx.x;
  const int nb = blockIdx.x * 128;
  char* AsB = (char*)As;
#pragma unroll
  for (int it = 0; it < 16; ++it) {
    int f = tid + 256 * it;          // 0..4095 over [128 rows][32 u32-pairs]
    int row = f >> 5, k4 = f & 31;   // k = 4*k4 .. 4*k4+3
    int n = nb + row;
    uint2 p;
    if (k4 < 16) {
      p = (n < NN) ? *(const uint2*)&aggxb[n * 32 + 2 * k4] : make_uint2(0u, 0u);
    } else {
      float4 v = (n < NN) ? *(const float4*)&x[n * 64 + 4 * (k4 - 16)]
                          : make_float4(0.f, 0.f, 0.f, 0.f);
      p.x = pack_bf16(v.x, v.y);
      p.y = pack_bf16(v.z, v.w);
    }
    int byte = row * 256 + k4 * 8;
    byte ^= (row & 7) << 4;
    *(uint2*)(AsB + byte) = p;
  }
  __syncthreads();
  const int lane = tid & 63;
  const int w = tid >> 6;
  const int lr = lane & 15;  // A row-in-tile / D col-in-tile
  const int lg = lane >> 4;  // k-group / D row-group
  f32x4 zero = {0.f, 0.f, 0.f, 0.f};
  f32x4 acc[8][2];
#pragma unroll
  for (int m = 0; m < 8; ++m) {
    acc[m][0] = zero;
    acc[m][1] = zero;
  }
#pragma unroll
  for (int s = 0; s < 4; ++s) {
    s16x8 bf[2];
#pragma unroll
    for (int nt = 0; nt < 2; ++nt)
      bf[nt] = *(const s16x8*)&Wpk0[(((2 * w + nt) * 4 + s) * 64 + lane) * 4];
#pragma unroll
    for (int m = 0; m < 8; ++m) {
      int row = 16 * m + lr;
      int byte = row * 256 + 64 * s + 16 * lg;
      byte ^= (row & 7) << 4;
      s16x8 af = *(const s16x8*)(AsB + byte);
      acc[m][0] = __builtin_amdgcn_mfma_f32_16x16x32_bf16(af, bf[0], acc[m][0], 0, 0, 0);
      acc[m][1] = __builtin_amdgcn_mfma_f32_16x16x32_bf16(af, bf[1], acc[m][1], 0, 0, 0);
    }
  }
  // Epilogue: h store (C layout: col = lane&15, row = 4*(lane>>4)+reg) + BN partials.
  float ps[2] = {0.f, 0.f}, qs[2] = {0.f, 0.f};
#pragma unroll
  for (int m = 0; m < 8; ++m) {
    int rowb = nb + 16 * m + 4 * lg;
#pragma unroll
    for (int nt = 0; nt < 2; ++nt) {
      int colg = 32 * w + 16 * nt + lr;
#pragma unroll
      for (int i = 0; i < 4; ++i) {
        float a = acc[m][nt][i];
        int n = rowb + i;
        if (n < NN) h[n * 128 + colg] = a;
        ps[nt] += a;
        qs[nt] += a * a;
      }
    }
  }
  __syncthreads();  // safe LDS reuse
  float* S = (float*)As;   // [4][128]
  float* Q = S + 512;      // [4][128]
#pragma unroll
  for (int nt = 0; nt < 2; ++nt) {
    int colg = 32 * w + 16 * nt + lr;
    S[lg * 128 + colg] = ps[nt];
    Q[lg * 128 + colg] = qs[nt];
  }
  __syncthreads();
  if (tid < 128) {
    float s = 0.f, q = 0.f;
#pragma unroll
    for (int g = 0; g < 4; ++g) { s += S[g * 128 + tid]; q += Q[g * 128 + tid]; }
    psum[blockIdx.x * 128 + tid] = s;
    pssq[blockIdx.x * 128 + tid] = q;
  }
}

// Parallel partial reduction -> scale/shift. 128 blocks (one per channel) x 64 lanes.
__global__ __launch_bounds__(64) void k_bnfin(
    const float* __restrict__ psum, const float* __restrict__ pssq,
    const float* __restrict__ gamma, const float* __restrict__ beta,
    float* __restrict__ scale, float* __restrict__ shift, int P) {
  const int c = blockIdx.x;
  const int t = threadIdx.x;
  float S = 0.f, Q = 0.f;
  for (int p = t; p < P; p += 64) {
    S += psum[p * 128 + c];
    Q += pssq[p * 128 + c];
  }
  for (int off = 32; off > 0; off >>= 1) {
    S += __shfl_down(S, off);
    Q += __shfl_down(Q, off);
  }
  if (t == 0) {
    float mean = S * (1.0f / NN);
    float var = fmaxf(Q * (1.0f / NN) - mean * mean, 0.f);
    float sc = gamma[c] * rsqrtf(var + EPSV);
    scale[c] = sc;
    shift[c] = beta[c] - mean * sc;
  }
}

// Pre-pack [Wrel1 | Wroot1] into bf16 MFMA B-fragment order. 16384 u32 = 64 KB.
__global__ __launch_bounds__(256) void k_packW(
    const float* __restrict__ Wrel, const float* __restrict__ Wroot,
    u32* __restrict__ Wpk) {
  int t = blockIdx.x * 256 + threadIdx.x;  // 0..16383
  int r = t & 3, lane = (t >> 2) & 63, s = (t >> 8) & 3, nt = t >> 10;
  int k = 32 * s + (lane >> 4) * 8 + 2 * r;
  int col = 16 * nt + (lane & 15);
  const float* W = (col < 128) ? &Wrel[k * 128 + col] : &Wroot[k * 128 + (col - 128)];
  Wpk[t] = pack_bf16(W[0], W[128]);
}

// t = relu(bn(h)); yb = bf16(t @ Wrel1) packed; h <- t @ Wroot1 (in place).
// MFMA bf16: 64-node tile, 4 waves, wave w owns cols [64w, 64w+64).
__global__ __launch_bounds__(256) void k_gemm_b(
    const u32* __restrict__ Wpk,
    const float* __restrict__ scale, const float* __restrict__ shift,
    u32* __restrict__ yb, float* __restrict__ h) {
  __shared__ u32 As[4096];  // 64 rows x 128 k bf16, XOR-swizzled
  const int tid = threadIdx.x;
  const int nb = blockIdx.x * 64;
  char* AsB = (char*)As;
#pragma unroll
  for (int it = 0; it < 8; ++it) {
    int f = tid + 256 * it;          // 0..2047 over [64 rows][32 float4]
    int row = f >> 5, k4 = f & 31;   // k = 4*k4 .. 4*k4+3
    int n = nb + row;
    float4 v = (n < NN) ? *(const float4*)&h[n * 128 + 4 * k4]
                        : make_float4(0.f, 0.f, 0.f, 0.f);
    float4 sc = *(const float4*)&scale[4 * k4];
    float4 sh = *(const float4*)&shift[4 * k4];
    float t0 = fmaxf(v.x * sc.x + sh.x, 0.f);
    float t1 = fmaxf(v.y * sc.y + sh.y, 0.f);
    float t2 = fmaxf(v.z * sc.z + sh.z, 0.f);
    float t3 = fmaxf(v.w * sc.w + sh.w, 0.f);
    uint2 p;
    p.x = pack_bf16(t0, t1);
    p.y = pack_bf16(t2, t3);
    int byte = row * 256 + k4 * 8;
    byte ^= (row & 7) << 4;
    *(uint2*)(AsB + byte) = p;
  }
  __syncthreads();
  const int lane = tid & 63;
  const int w = tid >> 6;
  const int lr = lane & 15;  // A row-in-tile / B,D col-in-tile
  const int lg = lane >> 4;  // k-group
  f32x4 zero = {0.f, 0.f, 0.f, 0.f};
  f32x4 acc[4][4];
#pragma unroll
  for (int m = 0; m < 4; ++m)
#pragma unroll
    for (int nt = 0; nt < 4; ++nt) acc[m][nt] = zero;

#pragma unroll
  for (int s = 0; s < 4; ++s) {
    s16x8 af[4];
#pragma unroll
    for (int m = 0; m < 4; ++m) {
      int row = 16 * m + lr;
      int byte = row * 256 + 64 * s + 16 * lg;
      byte ^= (row & 7) << 4;
      af[m] = *(const s16x8*)(AsB + byte);
    }
    s16x8 bf[4];
#pragma unroll
    for (int nt = 0; nt < 4; ++nt) {
      int gnt = w * 4 + nt;
      bf[nt] = *(const s16x8*)&Wpk[((gnt * 4 + s) * 64 + lane) * 4];
    }
#pragma unroll
    for (int m = 0; m < 4; ++m)
#pragma unroll
      for (int nt = 0; nt < 4; ++nt)
        acc[m][nt] = __builtin_amdgcn_mfma_f32_16x16x32_bf16(
            af[m], bf[nt], acc[m][nt], 0, 0, 0);
  }
  if (w < 2) {  // cols 0..127 -> yb (bf16 pairs)
#pragma unroll
    for (int m = 0; m < 4; ++m) {
#pragma unroll
      for (int nt = 0; nt < 4; ++nt) {
        int colg = 64 * w + 16 * nt + lr;
        int rowb = nb + 16 * m + 4 * lg;
        float a0 = acc[m][nt][0], a1 = acc[m][nt][1];
        float a2 = acc[m][nt][2], a3 = acc[m][nt][3];
        float o0 = __shfl_xor(a0, 1), o1 = __shfl_xor(a1, 1);
        float o2 = __shfl_xor(a2, 1), o3 = __shfl_xor(a3, 1);
        int c2 = colg >> 1;
        u32 q0, q1;
        int i0;
        if ((lane & 1) == 0) {
          q0 = pack_bf16(a0, o0); q1 = pack_bf16(a1, o1); i0 = 0;
        } else {
          q0 = pack_bf16(o2, a2); q1 = pack_bf16(o3, a3); i0 = 2;
        }
        int n0 = rowb + i0, n1 = rowb + i0 + 1;
        if (n0 < NN) yb[n0 * 64 + c2] = q0;
        if (n1 < NN) yb[n1 * 64 + c2] = q1;
      }
    }
  } else {  // cols 128..255 -> h (fp32)
#pragma unroll
    for (int m = 0; m < 4; ++m) {
#pragma unroll
      for (int nt = 0; nt < 4; ++nt) {
        int colg = 64 * (w - 2) + 16 * nt + lr;
        int rowb = nb + 16 * m + 4 * lg;
#pragma unroll
        for (int i = 0; i < 4; ++i) {
          int n = rowb + i;
          if (n < NN) h[n * 128 + colg] = acc[m][nt][i];
        }
      }
    }
  }
}

// h[n] += sum over incoming edges of unpack(yb[src]) + fused BN1 stat partials.
__global__ __launch_bounds__(256) void k_gather2(
    const u32* __restrict__ yb, const int* __restrict__ csr,
    const int* __restrict__ cur, const int* __restrict__ deg,
    float* __restrict__ h, float* __restrict__ psum, float* __restrict__ pssq) {
  int tid = blockIdx.x * 256 + threadIdx.x;
  int n = tid >> 4;
  int L = threadIdx.x & 15;
  int base = L << 2;   // u32 index within yb row
  int c0 = L << 3;     // first channel handled by this lane
  int i = cur[n];
  int end = i + deg[n];
  float lo0 = 0.f, lo1 = 0.f, lo2 = 0.f, lo3 = 0.f;
  float hi0 = 0.f, hi1 = 0.f, hi2 = 0.f, hi3 = 0.f;
  float mo0 = 0.f, mo1 = 0.f, mo2 = 0.f, mo3 = 0.f;
  float ni0 = 0.f, ni1 = 0.f, ni2 = 0.f, ni3 = 0.f;
  for (; i + 1 < end; i += 2) {
    int s0 = csr[i], s1 = csr[i + 1];
    uint4 v = *(const uint4*)&yb[s0 * 64 + base];
    uint4 w = *(const uint4*)&yb[s1 * 64 + base];
    lo0 += BFLO(v.x); hi0 += BFHI(v.x);
    lo1 += BFLO(v.y); hi1 += BFHI(v.y);
    lo2 += BFLO(v.z); hi2 += BFHI(v.z);
    lo3 += BFLO(v.w); hi3 += BFHI(v.w);
    mo0 += BFLO(w.x); ni0 += BFHI(w.x);
    mo1 += BFLO(w.y); ni1 += BFHI(w.y);
    mo2 += BFLO(w.z); ni2 += BFHI(w.z);
    mo3 += BFLO(w.w); ni3 += BFHI(w.w);
  }
  if (i < end) {
    int s = csr[i];
    uint4 v = *(const uint4*)&yb[s * 64 + base];
    lo0 += BFLO(v.x); hi0 += BFHI(v.x);
    lo1 += BFLO(v.y); hi1 += BFHI(v.y);
    lo2 += BFLO(v.z); hi2 += BFHI(v.z);
    lo3 += BFLO(v.w); hi3 += BFHI(v.w);
  }
  // channels: c0+0: lo0   c0+1: hi0   c0+2: lo1   c0+3: hi1
  //           c0+4: lo2   c0+5: hi2   c0+6: lo3   c0+7: hi3
  float4 A = *(const float4*)&h[n * 128 + c0];
  float4 B = *(const float4*)&h[n * 128 + c0 + 4];
  float4 R0 = make_float4(A.x + lo0 + mo0, A.y + hi0 + ni0,
                          A.z + lo1 + mo1, A.w + hi1 + ni1);
  float4 R1 = make_float4(B.x + lo2 + mo2, B.y + hi2 + ni2,
                          B.z + lo3 + mo3, B.w + hi3 + ni3);
  *(float4*)&h[n * 128 + c0]     = R0;
  *(float4*)&h[n * 128 + c0 + 4] = R1;
  // Fused BN1 stat partials: block covers 16 nodes x 128 channels.
  __shared__ float S[16 * 132], Q[16 * 132];
  const int nl = threadIdx.x >> 4;
  *(float4*)&S[nl * 132 + c0]     = R0;
  *(float4*)&S[nl * 132 + c0 + 4] = R1;
  *(float4*)&Q[nl * 132 + c0] =
      make_float4(R0.x * R0.x, R0.y * R0.y, R0.z * R0.z, R0.w * R0.w);
  *(float4*)&Q[nl * 132 + c0 + 4] =
      make_float4(R1.x * R1.x, R1.y * R1.y, R1.z * R1.z, R1.w * R1.w);
  __syncthreads();
  const int t = threadIdx.x;
  if (t < 128) {
    float s = 0.f, q = 0.f;
#pragma unroll
    for (int g = 0; g < 16; ++g) { s += S[g * 132 + t]; q += Q[g * 132 + t]; }
    psum[blockIdx.x * 128 + t] = s;
    pssq[blockIdx.x * 128 + t] = q;
  }
}

__global__ __launch_bounds__(256) void k_final(
    const float* __restrict__ h, const float* __restrict__ scale,
    const float* __restrict__ shift, float* __restrict__ out) {
  int tid = blockIdx.x * 256 + threadIdx.x;
  int base = tid << 2;
  int f4 = base & 127;
  float4 v = *(const float4*)&h[base];
  float4 sc = *(const float4*)&scale[f4];
  float4 sh = *(const float4*)&shift[f4];
  *(float4*)&out[base] = make_float4(v.x * sc.x + sh.x, v.y * sc.y + sh.y,
                                     v.z * sc.z + sh.z, v.w * sc.w + sh.w);
}

extern "C" void kernel_launch(void* const* d_in, const int* in_sizes, int n_in,
                              void* d_out, int out_size, void* d_ws, size_t ws_size,
                              hipStream_t stream) {
  if (ws_size < WS_NEEDED) {
    k_fallback<<<(NN * 128 + 255) / 256, 256, 0, stream>>>((float*)d_out);
    return;
  }
  const float* x      = (const float*)d_in[0];
  const int*   ei     = (const int*)d_in[1];
  const float* Wrel0  = (const float*)d_in[2];
  // d_in[3] = b_rel0: per-channel constant pre-BN -> cancels in BN, unused
  const float* Wroot0 = (const float*)d_in[4];
  const float* gamma0 = (const float*)d_in[5];
  const float* beta0  = (const float*)d_in[6];
  const float* Wrel1  = (const float*)d_in[7];
  // d_in[8] = b_rel1: unused (cancels in BN)
  const float* Wroot1 = (const float*)d_in[9];
  const float* gamma1 = (const float*)d_in[10];
  const float* beta1  = (const float*)d_in[11];

  float* aggx = (float*)d_ws;            // NN*64 region (aggxb, reused as yb)
  u32*   aggxb = (u32*)d_ws;             // NN*32 u32 packed bf16
  u32*   yb   = (u32*)d_ws;
  u32*   xb   = (u32*)(aggx + NN * 64);  // NN*32 (reused as Wpk/Wpk0 after gather_xb)
  u32*   Wpk  = xb;                      // 16384 u32 (64 KB), bf16 B frags layer 1
  u32*   Wpk0 = xb + 16384;              // 8192 u32 (32 KB), bf16 B frags layer 0
  float* st   = (float*)(xb + NN * 32);  // 1024 floats
  float* scale0 = st;       float* shift0 = st + 128;
  float* scale1 = st + 256; float* shift1 = st + 384;
  int* mode = (int*)(st + 512);
  int* bsum = (int*)(st + 576);          // 196 ints (ends at 772)
  int* binCur = (int*)(st + 772);        // 196 ints (zeroed in k_detect)
  int* deg = (int*)(st + 1024);          // NN
  int* cur = deg + NN;                   // NN
  int* csr = cur + NN;                   // NE
  float* psum = (float*)(csr + NE);      // 400000 (3125*128)
  float* pssq = psum + 400000;           // 400000
  int* rank = (int*)psum;                // NE ints (spans psum+pssq); dead later
  uint2* recs = (uint2*)(pssq + 400000); // 196*4096 uint2 (6.4 MB)
  float* h = (float*)d_out;              // h lives in d_out; k_final is in-place

  hipMemsetAsync(deg, 0, (size_t)NN * 4, stream);
  k_detect<<<1, 64, 0, stream>>>(ei, mode, binCur);
  k_hist<<<NE / 256, 256, 0, stream>>>(ei, mode, deg, rank);
  k_scan1<<<196, 256, 0, stream>>>(deg, bsum);
  k_scan3<<<196, 256, 0, stream>>>(deg, bsum, cur);
  k_binA<<<(NE + CHUNK - 1) / CHUNK, 256, 0, stream>>>(ei, mode, cur, rank, recs, binCur);
  k_binB<<<NBIN, 256, 0, stream>>>(recs, binCur, csr);

  k_pack<<<(NN * 32) / 256, 256, 0, stream>>>(x, xb);
  k_gather_xb<<<(NN * 16) / 256, 256, 0, stream>>>(xb, csr, cur, deg, aggxb);
  k_packW<<<64, 256, 0, stream>>>(Wrel1, Wroot1, Wpk);    // xb dead after gather_xb
  k_packW0<<<32, 256, 0, stream>>>(Wrel0, Wroot0, Wpk0);
  k_gemm_a<<<(NN + 127) / 128, 256, 0, stream>>>(x, aggxb, Wpk0, h, psum, pssq);
  k_bnfin<<<128, 64, 0, stream>>>(psum, pssq, gamma0, beta0, scale0, shift0, 391);
  k_gemm_b<<<(NN + 63) / 64, 256, 0, stream>>>(Wpk, scale0, shift0, yb, h);
  k_gather2<<<(NN * 16) / 256, 256, 0, stream>>>(yb, csr, cur, deg, h, psum, pssq);
  k_bnfin<<<128, 64, 0, stream>>>(psum, pssq, gamma1, beta1, scale1, shift1, 3125);
  k_final<<<(NN * 128) / 1024, 256, 0, stream>>>(h, scale1, shift1, (float*)d_out);
}

// Round 6
// 279.021 us; speedup vs baseline: 1.0461x; 1.0461x over previous
//
#include <hip/hip_runtime.h>

#define NN 50000
#define NE 800000
#define EPSV 1e-5f

typedef unsigned int u32;
typedef short s16x8 __attribute__((ext_vector_type(8)));
typedef float f32x4 __attribute__((ext_vector_type(4)));

// ws: aggxb/yb [NN*64 f] | xb [NN*32] | st [1024] | deg [NN] | cur [NN] | csr [NE]
//     | psum/pssq [2*400000] (rank aliases) | pedge [NE]
#define WS_NEEDED \
  ((size_t)(NN * 64 + NN * 32 + 1024 + NN + NN + NE + 2 * 400000 + NE) * 4)

__global__ void k_fallback(float* __restrict__ out) {
  int i = blockIdx.x * 256 + threadIdx.x;
  if (i < NN * 128) out[i] = 2.0f;
}

// mode: 1 = int64 (odd 32-bit words of first 32 values all zero), 0 = int32.
__global__ void k_detect(const int* __restrict__ ei, int* __restrict__ mode) {
  if (threadIdx.x == 0) {
    int all0 = 1;
    for (int i = 1; i < 64; i += 2) all0 &= (ei[i] == 0);
    *mode = all0;
  }
}

__device__ __forceinline__ void load_edge(const int* __restrict__ ei, int m, int e,
                                          int& src, int& dst) {
  if (m) { src = ei[e << 1]; dst = ei[(NE + e) << 1]; }
  else   { src = ei[e];      dst = ei[NE + e]; }
  src = min(max(src, 0), NN - 1);
  dst = min(max(dst, 0), NN - 1);
}

// rank trick: rank[e] = per-dst arrival order; placement then needs no atomic.
// Also emits packed edge record (src<<16 | dst; both < 50000 < 2^16) so
// k_place reads 3.2 MB instead of the 12.8 MB int64 edge_index again.
__global__ __launch_bounds__(256) void k_hist(
    const int* __restrict__ ei, const int* __restrict__ mode,
    int* __restrict__ deg, int* __restrict__ rank, u32* __restrict__ pedge) {
  int e = blockIdx.x * 256 + threadIdx.x;
  int src, dst;
  load_edge(ei, *mode, e, src, dst);
  rank[e] = atomicAdd(&deg[dst], 1);
  pedge[e] = ((u32)src << 16) | (u32)dst;
}

// Stage 1: per-256-chunk sums of deg. 196 blocks.
__global__ __launch_bounds__(256) void k_scan1(
    const int* __restrict__ deg, int* __restrict__ bsum) {
  const int b = blockIdx.x, t = threadIdx.x;
  const int lane = t & 63, wave = t >> 6;
  int idx = b * 256 + t;
  int v = (idx < NN) ? deg[idx] : 0;
  for (int off = 32; off > 0; off >>= 1) v += __shfl_down(v, off);
  __shared__ int wt[4];
  if (lane == 0) wt[wave] = v;
  __syncthreads();
  if (t == 0) bsum[b] = wt[0] + wt[1] + wt[2] + wt[3];
}

// Stage 2: block offset = reduce(bsum[0..b)), then block-wide exclusive scan.
__global__ __launch_bounds__(256) void k_scan3(
    const int* __restrict__ deg, const int* __restrict__ bsum, int* __restrict__ cur) {
  const int b = blockIdx.x, t = threadIdx.x;
  const int lane = t & 63, wave = t >> 6;
  __shared__ int wt[4];
  __shared__ int boff;
  int pv = (t < b) ? bsum[t] : 0;  // b <= 195 < 256
  int r = pv;
  for (int off = 32; off > 0; off >>= 1) r += __shfl_down(r, off);
  if (lane == 0) wt[wave] = r;
  __syncthreads();
  if (t == 0) boff = wt[0] + wt[1] + wt[2] + wt[3];
  __syncthreads();
  int idx = b * 256 + t;
  int v = (idx < NN) ? deg[idx] : 0;
  int incl = v;
  for (int off = 1; off < 64; off <<= 1) {
    int u = __shfl_up(incl, off);
    if (lane >= off) incl += u;
  }
  if (lane == 63) wt[wave] = incl;
  __syncthreads();
  int woff = 0;
  for (int w = 0; w < wave; ++w) woff += wt[w];
  if (idx < NN) cur[idx] = boff + woff + incl - v;  // exclusive start offsets
}

// Atomic-free: pos = start[dst] + rank[e]. cur stays = start offsets.
__global__ __launch_bounds__(256) void k_place(
    const u32* __restrict__ pedge, const int* __restrict__ cur,
    const int* __restrict__ rank, int* __restrict__ csr) {
  int e = blockIdx.x * 256 + threadIdx.x;
  u32 pe = pedge[e];
  int dst = (int)(pe & 0xffffu);
  int src = (int)(pe >> 16);
  csr[cur[dst] + rank[e]] = src;
}

__device__ __forceinline__ u32 pack_bf16(float lo, float hi) {
  union { float f; u32 u; } a, b;
  a.f = lo; b.f = hi;
  u32 ua = a.u + 0x7fffu + ((a.u >> 16) & 1u);
  u32 ub = b.u + 0x7fffu + ((b.u >> 16) & 1u);
  return (ua >> 16) | (ub & 0xffff0000u);
}
#define BFLO(u) __uint_as_float((u) << 16)
#define BFHI(u) __uint_as_float((u) & 0xffff0000u)

// xb[n*32+c] = pack(x[n*64+2c], x[n*64+2c+1])
__global__ __launch_bounds__(256) void k_pack(
    const float* __restrict__ x, u32* __restrict__ xb) {
  int i = blockIdx.x * 256 + threadIdx.x;  // over NN*32
  int n = i >> 5, c = i & 31;
  float2 v = *(const float2*)&x[n * 64 + c * 2];
  xb[i] = pack_bf16(v.x, v.y);
}

// aggxb[n*32+2L..2L+1] = packed-bf16 sums over incoming edges of xb[src].
// 16 lanes/node, uint2/lane. bf16 output: identical rounding to what k_gemm_a
// staging did before, but halves aggx traffic (12.8 -> 6.4 MB each way).
__global__ __launch_bounds__(256) void k_gather_xb(
    const u32* __restrict__ xb, const int* __restrict__ csr,
    const int* __restrict__ cur, const int* __restrict__ deg,
    u32* __restrict__ aggxb) {
  int tid = blockIdx.x * 256 + threadIdx.x;
  int n = tid >> 4, L = tid & 15;
  int i = cur[n];
  int end = i + deg[n];
  float a0 = 0.f, a1 = 0.f, a2 = 0.f, a3 = 0.f;
  float b0 = 0.f, b1 = 0.f, b2 = 0.f, b3 = 0.f;
  for (; i + 1 < end; i += 2) {
    int s0 = csr[i], s1 = csr[i + 1];
    uint2 u = *(const uint2*)&xb[s0 * 32 + 2 * L];
    uint2 w = *(const uint2*)&xb[s1 * 32 + 2 * L];
    a0 += BFLO(u.x); a1 += BFHI(u.x); a2 += BFLO(u.y); a3 += BFHI(u.y);
    b0 += BFLO(w.x); b1 += BFHI(w.x); b2 += BFLO(w.y); b3 += BFHI(w.y);
  }
  if (i < end) {
    int s0 = csr[i];
    uint2 u = *(const uint2*)&xb[s0 * 32 + 2 * L];
    a0 += BFLO(u.x); a1 += BFHI(u.x); a2 += BFLO(u.y); a3 += BFHI(u.y);
  }
  uint2 o;
  o.x = pack_bf16(a0 + b0, a1 + b1);
  o.y = pack_bf16(a2 + b2, a3 + b3);
  *(uint2*)&aggxb[n * 32 + 2 * L] = o;
}

// Pre-pack [Wrel0 ; Wroot0] (stacked K=128, N=128) into bf16 MFMA B-fragment
// order. 8192 u32 = 32 KB.
__global__ __launch_bounds__(256) void k_packW0(
    const float* __restrict__ Wrel, const float* __restrict__ Wroot,
    u32* __restrict__ Wpk0) {
  int t = blockIdx.x * 256 + threadIdx.x;  // 0..8191
  int r = t & 3, lane = (t >> 2) & 63, s = (t >> 8) & 3, nt = t >> 10;
  int k = 32 * s + (lane >> 4) * 8 + 2 * r;
  int col = 16 * nt + (lane & 15);
  const float* W = (k < 64) ? &Wrel[k * 128 + col] : &Wroot[(k - 64) * 128 + col];
  Wpk0[t] = pack_bf16(W[0], W[128]);
}

// h = [aggx | x] @ [Wrel0 ; Wroot0] (M=NN, K=128, N=128) + fused BN0 partials.
// MFMA bf16: 128-node tile, 4 waves, wave w owns cols [32w, 32w+32).
// A staged in 32KB XOR-swizzled LDS; aggx half copied pre-packed from aggxb.
__global__ __launch_bounds__(256) void k_gemm_a(
    const float* __restrict__ x, const u32* __restrict__ aggxb,
    const u32* __restrict__ Wpk0,
    float* __restrict__ h, float* __restrict__ psum, float* __restrict__ pssq) {
  __shared__ u32 As[8192];  // 128 rows x 128 k bf16, XOR-swizzled
  const int tid = threadIdx.x;
  const int nb = blockIdx.x * 128;
  char* AsB = (char*)As;
#pragma unroll
  for (int it = 0; it < 16; ++it) {
    int f = tid + 256 * it;          // 0..4095 over [128 rows][32 u32-pairs]
    int row = f >> 5, k4 = f & 31;   // k = 4*k4 .. 4*k4+3
    int n = nb + row;
    uint2 p;
    if (k4 < 16) {
      p = (n < NN) ? *(const uint2*)&aggxb[n * 32 + 2 * k4] : make_uint2(0u, 0u);
    } else {
      float4 v = (n < NN) ? *(const float4*)&x[n * 64 + 4 * (k4 - 16)]
                          : make_float4(0.f, 0.f, 0.f, 0.f);
      p.x = pack_bf16(v.x, v.y);
      p.y = pack_bf16(v.z, v.w);
    }
    int byte = row * 256 + k4 * 8;
    byte ^= (row & 7) << 4;
    *(uint2*)(AsB + byte) = p;
  }
  __syncthreads();
  const int lane = tid & 63;
  const int w = tid >> 6;
  const int lr = lane & 15;  // A row-in-tile / D col-in-tile
  const int lg = lane >> 4;  // k-group / D row-group
  f32x4 zero = {0.f, 0.f, 0.f, 0.f};
  f32x4 acc[8][2];
#pragma unroll
  for (int m = 0; m < 8; ++m) {
    acc[m][0] = zero;
    acc[m][1] = zero;
  }
#pragma unroll
  for (int s = 0; s < 4; ++s) {
    s16x8 bf[2];
#pragma unroll
    for (int nt = 0; nt < 2; ++nt)
      bf[nt] = *(const s16x8*)&Wpk0[(((2 * w + nt) * 4 + s) * 64 + lane) * 4];
#pragma unroll
    for (int m = 0; m < 8; ++m) {
      int row = 16 * m + lr;
      int byte = row * 256 + 64 * s + 16 * lg;
      byte ^= (row & 7) << 4;
      s16x8 af = *(const s16x8*)(AsB + byte);
      acc[m][0] = __builtin_amdgcn_mfma_f32_16x16x32_bf16(af, bf[0], acc[m][0], 0, 0, 0);
      acc[m][1] = __builtin_amdgcn_mfma_f32_16x16x32_bf16(af, bf[1], acc[m][1], 0, 0, 0);
    }
  }
  // Epilogue: h store (C layout: col = lane&15, row = 4*(lane>>4)+reg) + BN partials.
  float ps[2] = {0.f, 0.f}, qs[2] = {0.f, 0.f};
#pragma unroll
  for (int m = 0; m < 8; ++m) {
    int rowb = nb + 16 * m + 4 * lg;
#pragma unroll
    for (int nt = 0; nt < 2; ++nt) {
      int colg = 32 * w + 16 * nt + lr;
#pragma unroll
      for (int i = 0; i < 4; ++i) {
        float a = acc[m][nt][i];
        int n = rowb + i;
        if (n < NN) h[n * 128 + colg] = a;
        ps[nt] += a;
        qs[nt] += a * a;
      }
    }
  }
  __syncthreads();  // safe LDS reuse
  float* S = (float*)As;   // [4][128]
  float* Q = S + 512;      // [4][128]
#pragma unroll
  for (int nt = 0; nt < 2; ++nt) {
    int colg = 32 * w + 16 * nt + lr;
    S[lg * 128 + colg] = ps[nt];
    Q[lg * 128 + colg] = qs[nt];
  }
  __syncthreads();
  if (tid < 128) {
    float s = 0.f, q = 0.f;
#pragma unroll
    for (int g = 0; g < 4; ++g) { s += S[g * 128 + tid]; q += Q[g * 128 + tid]; }
    psum[blockIdx.x * 128 + tid] = s;
    pssq[blockIdx.x * 128 + tid] = q;
  }
}

// Parallel partial reduction -> scale/shift. 128 blocks (one per channel) x 64 lanes.
__global__ __launch_bounds__(64) void k_bnfin(
    const float* __restrict__ psum, const float* __restrict__ pssq,
    const float* __restrict__ gamma, const float* __restrict__ beta,
    float* __restrict__ scale, float* __restrict__ shift, int P) {
  const int c = blockIdx.x;
  const int t = threadIdx.x;
  float S = 0.f, Q = 0.f;
  for (int p = t; p < P; p += 64) {
    S += psum[p * 128 + c];
    Q += pssq[p * 128 + c];
  }
  for (int off = 32; off > 0; off >>= 1) {
    S += __shfl_down(S, off);
    Q += __shfl_down(Q, off);
  }
  if (t == 0) {
    float mean = S * (1.0f / NN);
    float var = fmaxf(Q * (1.0f / NN) - mean * mean, 0.f);
    float sc = gamma[c] * rsqrtf(var + EPSV);
    scale[c] = sc;
    shift[c] = beta[c] - mean * sc;
  }
}

// Pre-pack [Wrel1 | Wroot1] into bf16 MFMA B-fragment order. 16384 u32 = 64 KB.
__global__ __launch_bounds__(256) void k_packW(
    const float* __restrict__ Wrel, const float* __restrict__ Wroot,
    u32* __restrict__ Wpk) {
  int t = blockIdx.x * 256 + threadIdx.x;  // 0..16383
  int r = t & 3, lane = (t >> 2) & 63, s = (t >> 8) & 3, nt = t >> 10;
  int k = 32 * s + (lane >> 4) * 8 + 2 * r;
  int col = 16 * nt + (lane & 15);
  const float* W = (col < 128) ? &Wrel[k * 128 + col] : &Wroot[k * 128 + (col - 128)];
  Wpk[t] = pack_bf16(W[0], W[128]);
}

// t = relu(bn(h)); yb = bf16(t @ Wrel1) packed; h <- t @ Wroot1 (in place).
// MFMA bf16: 64-node tile, 4 waves, wave w owns cols [64w, 64w+64).
__global__ __launch_bounds__(256) void k_gemm_b(
    const u32* __restrict__ Wpk,
    const float* __restrict__ scale, const float* __restrict__ shift,
    u32* __restrict__ yb, float* __restrict__ h) {
  __shared__ u32 As[4096];  // 64 rows x 128 k bf16, XOR-swizzled
  const int tid = threadIdx.x;
  const int nb = blockIdx.x * 64;
  char* AsB = (char*)As;
#pragma unroll
  for (int it = 0; it < 8; ++it) {
    int f = tid + 256 * it;          // 0..2047 over [64 rows][32 float4]
    int row = f >> 5, k4 = f & 31;   // k = 4*k4 .. 4*k4+3
    int n = nb + row;
    float4 v = (n < NN) ? *(const float4*)&h[n * 128 + 4 * k4]
                        : make_float4(0.f, 0.f, 0.f, 0.f);
    float4 sc = *(const float4*)&scale[4 * k4];
    float4 sh = *(const float4*)&shift[4 * k4];
    float t0 = fmaxf(v.x * sc.x + sh.x, 0.f);
    float t1 = fmaxf(v.y * sc.y + sh.y, 0.f);
    float t2 = fmaxf(v.z * sc.z + sh.z, 0.f);
    float t3 = fmaxf(v.w * sc.w + sh.w, 0.f);
    uint2 p;
    p.x = pack_bf16(t0, t1);
    p.y = pack_bf16(t2, t3);
    int byte = row * 256 + k4 * 8;
    byte ^= (row & 7) << 4;
    *(uint2*)(AsB + byte) = p;
  }
  __syncthreads();
  const int lane = tid & 63;
  const int w = tid >> 6;
  const int lr = lane & 15;  // A row-in-tile / B,D col-in-tile
  const int lg = lane >> 4;  // k-group
  f32x4 zero = {0.f, 0.f, 0.f, 0.f};
  f32x4 acc[4][4];
#pragma unroll
  for (int m = 0; m < 4; ++m)
#pragma unroll
    for (int nt = 0; nt < 4; ++nt) acc[m][nt] = zero;

#pragma unroll
  for (int s = 0; s < 4; ++s) {
    s16x8 af[4];
#pragma unroll
    for (int m = 0; m < 4; ++m) {
      int row = 16 * m + lr;
      int byte = row * 256 + 64 * s + 16 * lg;
      byte ^= (row & 7) << 4;
      af[m] = *(const s16x8*)(AsB + byte);
    }
    s16x8 bf[4];
#pragma unroll
    for (int nt = 0; nt < 4; ++nt) {
      int gnt = w * 4 + nt;
      bf[nt] = *(const s16x8*)&Wpk[((gnt * 4 + s) * 64 + lane) * 4];
    }
#pragma unroll
    for (int m = 0; m < 4; ++m)
#pragma unroll
      for (int nt = 0; nt < 4; ++nt)
        acc[m][nt] = __builtin_amdgcn_mfma_f32_16x16x32_bf16(
            af[m], bf[nt], acc[m][nt], 0, 0, 0);
  }
  if (w < 2) {  // cols 0..127 -> yb (bf16 pairs)
#pragma unroll
    for (int m = 0; m < 4; ++m) {
#pragma unroll
      for (int nt = 0; nt < 4; ++nt) {
        int colg = 64 * w + 16 * nt + lr;
        int rowb = nb + 16 * m + 4 * lg;
        float a0 = acc[m][nt][0], a1 = acc[m][nt][1];
        float a2 = acc[m][nt][2], a3 = acc[m][nt][3];
        float o0 = __shfl_xor(a0, 1), o1 = __shfl_xor(a1, 1);
        float o2 = __shfl_xor(a2, 1), o3 = __shfl_xor(a3, 1);
        int c2 = colg >> 1;
        u32 q0, q1;
        int i0;
        if ((lane & 1) == 0) {
          q0 = pack_bf16(a0, o0); q1 = pack_bf16(a1, o1); i0 = 0;
        } else {
          q0 = pack_bf16(o2, a2); q1 = pack_bf16(o3, a3); i0 = 2;
        }
        int n0 = rowb + i0, n1 = rowb + i0 + 1;
        if (n0 < NN) yb[n0 * 64 + c2] = q0;
        if (n1 < NN) yb[n1 * 64 + c2] = q1;
      }
    }
  } else {  // cols 128..255 -> h (fp32)
#pragma unroll
    for (int m = 0; m < 4; ++m) {
#pragma unroll
      for (int nt = 0; nt < 4; ++nt) {
        int colg = 64 * (w - 2) + 16 * nt + lr;
        int rowb = nb + 16 * m + 4 * lg;
#pragma unroll
        for (int i = 0; i < 4; ++i) {
          int n = rowb + i;
          if (n < NN) h[n * 128 + colg] = acc[m][nt][i];
        }
      }
    }
  }
}

// h[n] += sum over incoming edges of unpack(yb[src]) + fused BN1 stat partials.
__global__ __launch_bounds__(256) void k_gather2(
    const u32* __restrict__ yb, const int* __restrict__ csr,
    const int* __restrict__ cur, const int* __restrict__ deg,
    float* __restrict__ h, float* __restrict__ psum, float* __restrict__ pssq) {
  int tid = blockIdx.x * 256 + threadIdx.x;
  int n = tid >> 4;
  int L = threadIdx.x & 15;
  int base = L << 2;   // u32 index within yb row
  int c0 = L << 3;     // first channel handled by this lane
  int i = cur[n];
  int end = i + deg[n];
  float lo0 = 0.f, lo1 = 0.f, lo2 = 0.f, lo3 = 0.f;
  float hi0 = 0.f, hi1 = 0.f, hi2 = 0.f, hi3 = 0.f;
  float mo0 = 0.f, mo1 = 0.f, mo2 = 0.f, mo3 = 0.f;
  float ni0 = 0.f, ni1 = 0.f, ni2 = 0.f, ni3 = 0.f;
  for (; i + 1 < end; i += 2) {
    int s0 = csr[i], s1 = csr[i + 1];
    uint4 v = *(const uint4*)&yb[s0 * 64 + base];
    uint4 w = *(const uint4*)&yb[s1 * 64 + base];
    lo0 += BFLO(v.x); hi0 += BFHI(v.x);
    lo1 += BFLO(v.y); hi1 += BFHI(v.y);
    lo2 += BFLO(v.z); hi2 += BFHI(v.z);
    lo3 += BFLO(v.w); hi3 += BFHI(v.w);
    mo0 += BFLO(w.x); ni0 += BFHI(w.x);
    mo1 += BFLO(w.y); ni1 += BFHI(w.y);
    mo2 += BFLO(w.z); ni2 += BFHI(w.z);
    mo3 += BFLO(w.w); ni3 += BFHI(w.w);
  }
  if (i < end) {
    int s = csr[i];
    uint4 v = *(const uint4*)&yb[s * 64 + base];
    lo0 += BFLO(v.x); hi0 += BFHI(v.x);
    lo1 += BFLO(v.y); hi1 += BFHI(v.y);
    lo2 += BFLO(v.z); hi2 += BFHI(v.z);
    lo3 += BFLO(v.w); hi3 += BFHI(v.w);
  }
  // channels: c0+0: lo0   c0+1: hi0   c0+2: lo1   c0+3: hi1
  //           c0+4: lo2   c0+5: hi2   c0+6: lo3   c0+7: hi3
  float4 A = *(const float4*)&h[n * 128 + c0];
  float4 B = *(const float4*)&h[n * 128 + c0 + 4];
  float4 R0 = make_float4(A.x + lo0 + mo0, A.y + hi0 + ni0,
                          A.z + lo1 + mo1, A.w + hi1 + ni1);
  float4 R1 = make_float4(B.x + lo2 + mo2, B.y + hi2 + ni2,
                          B.z + lo3 + mo3, B.w + hi3 + ni3);
  *(float4*)&h[n * 128 + c0]     = R0;
  *(float4*)&h[n * 128 + c0 + 4] = R1;
  // Fused BN1 stat partials: block covers 16 nodes x 128 channels.
  __shared__ float S[16 * 132], Q[16 * 132];
  const int nl = threadIdx.x >> 4;
  *(float4*)&S[nl * 132 + c0]     = R0;
  *(float4*)&S[nl * 132 + c0 + 4] = R1;
  *(float4*)&Q[nl * 132 + c0] =
      make_float4(R0.x * R0.x, R0.y * R0.y, R0.z * R0.z, R0.w * R0.w);
  *(float4*)&Q[nl * 132 + c0 + 4] =
      make_float4(R1.x * R1.x, R1.y * R1.y, R1.z * R1.z, R1.w * R1.w);
  __syncthreads();
  const int t = threadIdx.x;
  if (t < 128) {
    float s = 0.f, q = 0.f;
#pragma unroll
    for (int g = 0; g < 16; ++g) { s += S[g * 132 + t]; q += Q[g * 132 + t]; }
    psum[blockIdx.x * 128 + t] = s;
    pssq[blockIdx.x * 128 + t] = q;
  }
}

__global__ __launch_bounds__(256) void k_final(
    const float* __restrict__ h, const float* __restrict__ scale,
    const float* __restrict__ shift, float* __restrict__ out) {
  int tid = blockIdx.x * 256 + threadIdx.x;
  int base = tid << 2;
  int f4 = base & 127;
  float4 v = *(const float4*)&h[base];
  float4 sc = *(const float4*)&scale[f4];
  float4 sh = *(const float4*)&shift[f4];
  *(float4*)&out[base] = make_float4(v.x * sc.x + sh.x, v.y * sc.y + sh.y,
                                     v.z * sc.z + sh.z, v.w * sc.w + sh.w);
}

extern "C" void kernel_launch(void* const* d_in, const int* in_sizes, int n_in,
                              void* d_out, int out_size, void* d_ws, size_t ws_size,
                              hipStream_t stream) {
  if (ws_size < WS_NEEDED) {
    k_fallback<<<(NN * 128 + 255) / 256, 256, 0, stream>>>((float*)d_out);
    return;
  }
  const float* x      = (const float*)d_in[0];
  const int*   ei     = (const int*)d_in[1];
  const float* Wrel0  = (const float*)d_in[2];
  // d_in[3] = b_rel0: per-channel constant pre-BN -> cancels in BN, unused
  const float* Wroot0 = (const float*)d_in[4];
  const float* gamma0 = (const float*)d_in[5];
  const float* beta0  = (const float*)d_in[6];
  const float* Wrel1  = (const float*)d_in[7];
  // d_in[8] = b_rel1: unused (cancels in BN)
  const float* Wroot1 = (const float*)d_in[9];
  const float* gamma1 = (const float*)d_in[10];
  const float* beta1  = (const float*)d_in[11];

  float* aggx = (float*)d_ws;            // NN*64 region (aggxb, reused as yb)
  u32*   aggxb = (u32*)d_ws;             // NN*32 u32 packed bf16
  u32*   yb   = (u32*)d_ws;
  u32*   xb   = (u32*)(aggx + NN * 64);  // NN*32 (reused as Wpk/Wpk0 after gather_xb)
  u32*   Wpk  = xb;                      // 16384 u32 (64 KB), bf16 B frags layer 1
  u32*   Wpk0 = xb + 16384;              // 8192 u32 (32 KB), bf16 B frags layer 0
  float* st   = (float*)(xb + NN * 32);  // 1024 floats
  float* scale0 = st;       float* shift0 = st + 128;
  float* scale1 = st + 256; float* shift1 = st + 384;
  int* mode = (int*)(st + 512);
  int* bsum = (int*)(st + 576);          // 196 ints
  int* deg = (int*)(st + 1024);          // NN
  int* cur = deg + NN;                   // NN
  int* csr = cur + NN;                   // NE
  float* psum = (float*)(csr + NE);      // 400000 (3125*128)
  float* pssq = psum + 400000;           // 400000
  int* rank = (int*)psum;                // NE ints (spans psum+pssq); dead later
  u32* pedge = (u32*)(pssq + 400000);    // NE packed edges (src<<16|dst)
  float* h = (float*)d_out;              // h lives in d_out; k_final is in-place

  hipMemsetAsync(deg, 0, (size_t)NN * 4, stream);
  k_detect<<<1, 64, 0, stream>>>(ei, mode);
  k_hist<<<NE / 256, 256, 0, stream>>>(ei, mode, deg, rank, pedge);
  k_scan1<<<196, 256, 0, stream>>>(deg, bsum);
  k_scan3<<<196, 256, 0, stream>>>(deg, bsum, cur);
  k_place<<<NE / 256, 256, 0, stream>>>(pedge, cur, rank, csr);

  k_pack<<<(NN * 32) / 256, 256, 0, stream>>>(x, xb);
  k_gather_xb<<<(NN * 16) / 256, 256, 0, stream>>>(xb, csr, cur, deg, aggxb);
  k_packW<<<64, 256, 0, stream>>>(Wrel1, Wroot1, Wpk);    // xb dead after gather_xb
  k_packW0<<<32, 256, 0, stream>>>(Wrel0, Wroot0, Wpk0);
  k_gemm_a<<<(NN + 127) / 128, 256, 0, stream>>>(x, aggxb, Wpk0, h, psum, pssq);
  k_bnfin<<<128, 64, 0, stream>>>(psum, pssq, gamma0, beta0, scale0, shift0, 391);
  k_gemm_b<<<(NN + 63) / 64, 256, 0, stream>>>(Wpk, scale0, shift0, yb, h);
  k_gather2<<<(NN * 16) / 256, 256, 0, stream>>>(yb, csr, cur, deg, h, psum, pssq);
  k_bnfin<<<128, 64, 0, stream>>>(psum, pssq, gamma1, beta1, scale1, shift1, 3125);
  k_final<<<(NN * 128) / 1024, 256, 0, stream>>>(h, scale1, shift1, (float*)d_out);
}

// Round 7
// 269.128 us; speedup vs baseline: 1.0845x; 1.0368x over previous
//
#include <hip/hip_runtime.h>

#define NN 50000
#define NE 800000
#define EPSV 1e-5f

typedef unsigned int u32;
typedef short s16x8 __attribute__((ext_vector_type(8)));
typedef float f32x4 __attribute__((ext_vector_type(4)));

// ws layout (4B units):
//   A: aggxb/yb   [NN*64]
//   xb            [NN*32]   (live until k_gemm_a)
//   st            [1024]
//   deg/cur/csr   [NN + NN + NE]
//   psum/pssq     [2*400000] (rank aliases psum/pssq; dead before gemm_a)
//   pedge         [NE]
//   Wpk/Wpk0      [16384 + 8192]
//   hb            [NN*64]   (bf16 layer-0 h)
#define WS_NEEDED \
  ((size_t)(NN * 64 + NN * 32 + 1024 + NN + NN + NE + 2 * 400000 + NE + \
            16384 + 8192 + NN * 64) * 4)

__global__ void k_fallback(float* __restrict__ out) {
  int i = blockIdx.x * 256 + threadIdx.x;
  if (i < NN * 128) out[i] = 2.0f;
}

// mode: 1 = int64 (odd 32-bit words of first 32 values all zero), 0 = int32.
__global__ void k_detect(const int* __restrict__ ei, int* __restrict__ mode) {
  if (threadIdx.x == 0) {
    int all0 = 1;
    for (int i = 1; i < 64; i += 2) all0 &= (ei[i] == 0);
    *mode = all0;
  }
}

__device__ __forceinline__ void load_edge(const int* __restrict__ ei, int m, int e,
                                          int& src, int& dst) {
  if (m) { src = ei[e << 1]; dst = ei[(NE + e) << 1]; }
  else   { src = ei[e];      dst = ei[NE + e]; }
  src = min(max(src, 0), NN - 1);
  dst = min(max(dst, 0), NN - 1);
}

// rank trick: rank[e] = per-dst arrival order; placement then needs no atomic.
// Also emits packed edge record (src<<16 | dst; both < 2^16).
__global__ __launch_bounds__(256) void k_hist(
    const int* __restrict__ ei, const int* __restrict__ mode,
    int* __restrict__ deg, int* __restrict__ rank, u32* __restrict__ pedge) {
  int e = blockIdx.x * 256 + threadIdx.x;
  int src, dst;
  load_edge(ei, *mode, e, src, dst);
  rank[e] = atomicAdd(&deg[dst], 1);
  pedge[e] = ((u32)src << 16) | (u32)dst;
}

// Stage 1: per-256-chunk sums of deg. 196 blocks.
__global__ __launch_bounds__(256) void k_scan1(
    const int* __restrict__ deg, int* __restrict__ bsum) {
  const int b = blockIdx.x, t = threadIdx.x;
  const int lane = t & 63, wave = t >> 6;
  int idx = b * 256 + t;
  int v = (idx < NN) ? deg[idx] : 0;
  for (int off = 32; off > 0; off >>= 1) v += __shfl_down(v, off);
  __shared__ int wt[4];
  if (lane == 0) wt[wave] = v;
  __syncthreads();
  if (t == 0) bsum[b] = wt[0] + wt[1] + wt[2] + wt[3];
}

// Stage 2: block offset = reduce(bsum[0..b)), then block-wide exclusive scan.
__global__ __launch_bounds__(256) void k_scan3(
    const int* __restrict__ deg, const int* __restrict__ bsum, int* __restrict__ cur) {
  const int b = blockIdx.x, t = threadIdx.x;
  const int lane = t & 63, wave = t >> 6;
  __shared__ int wt[4];
  __shared__ int boff;
  int pv = (t < b) ? bsum[t] : 0;  // b <= 195 < 256
  int r = pv;
  for (int off = 32; off > 0; off >>= 1) r += __shfl_down(r, off);
  if (lane == 0) wt[wave] = r;
  __syncthreads();
  if (t == 0) boff = wt[0] + wt[1] + wt[2] + wt[3];
  __syncthreads();
  int idx = b * 256 + t;
  int v = (idx < NN) ? deg[idx] : 0;
  int incl = v;
  for (int off = 1; off < 64; off <<= 1) {
    int u = __shfl_up(incl, off);
    if (lane >= off) incl += u;
  }
  if (lane == 63) wt[wave] = incl;
  __syncthreads();
  int woff = 0;
  for (int w = 0; w < wave; ++w) woff += wt[w];
  if (idx < NN) cur[idx] = boff + woff + incl - v;  // exclusive start offsets
}

// Atomic-free: pos = start[dst] + rank[e]. cur stays = start offsets.
__global__ __launch_bounds__(256) void k_place(
    const u32* __restrict__ pedge, const int* __restrict__ cur,
    const int* __restrict__ rank, int* __restrict__ csr) {
  int e = blockIdx.x * 256 + threadIdx.x;
  u32 pe = pedge[e];
  int dst = (int)(pe & 0xffffu);
  int src = (int)(pe >> 16);
  csr[cur[dst] + rank[e]] = src;
}

__device__ __forceinline__ u32 pack_bf16(float lo, float hi) {
  union { float f; u32 u; } a, b;
  a.f = lo; b.f = hi;
  u32 ua = a.u + 0x7fffu + ((a.u >> 16) & 1u);
  u32 ub = b.u + 0x7fffu + ((b.u >> 16) & 1u);
  return (ua >> 16) | (ub & 0xffff0000u);
}
#define BFLO(u) __uint_as_float((u) << 16)
#define BFHI(u) __uint_as_float((u) & 0xffff0000u)

// Merged prep: xb pack (blocks 0..6249), Wpk1 pack (6250..6313),
// Wpk0 pack (6314..6345). Saves 2 launches.
__global__ __launch_bounds__(256) void k_prep(
    const float* __restrict__ x, u32* __restrict__ xb,
    const float* __restrict__ Wrel1, const float* __restrict__ Wroot1,
    u32* __restrict__ Wpk,
    const float* __restrict__ Wrel0, const float* __restrict__ Wroot0,
    u32* __restrict__ Wpk0) {
  const int b = blockIdx.x;
  if (b < 6250) {  // xb[n*32+c] = pack(x[n*64+2c], x[n*64+2c+1]) over NN*32
    int i = b * 256 + threadIdx.x;
    int n = i >> 5, c = i & 31;
    float2 v = *(const float2*)&x[n * 64 + c * 2];
    xb[i] = pack_bf16(v.x, v.y);
  } else if (b < 6314) {  // [Wrel1 | Wroot1] -> bf16 B frags (16384 u32)
    int t = (b - 6250) * 256 + threadIdx.x;
    int r = t & 3, lane = (t >> 2) & 63, s = (t >> 8) & 3, nt = t >> 10;
    int k = 32 * s + (lane >> 4) * 8 + 2 * r;
    int col = 16 * nt + (lane & 15);
    const float* W = (col < 128) ? &Wrel1[k * 128 + col]
                                 : &Wroot1[k * 128 + (col - 128)];
    Wpk[t] = pack_bf16(W[0], W[128]);
  } else {  // [Wrel0 ; Wroot0] stacked K -> bf16 B frags (8192 u32)
    int t = (b - 6314) * 256 + threadIdx.x;
    int r = t & 3, lane = (t >> 2) & 63, s = (t >> 8) & 3, nt = t >> 10;
    int k = 32 * s + (lane >> 4) * 8 + 2 * r;
    int col = 16 * nt + (lane & 15);
    const float* W = (k < 64) ? &Wrel0[k * 128 + col]
                              : &Wroot0[(k - 64) * 128 + col];
    Wpk0[t] = pack_bf16(W[0], W[128]);
  }
}

// aggxb[n*32+2L..2L+1] = packed-bf16 sums over incoming edges of xb[src].
__global__ __launch_bounds__(256) void k_gather_xb(
    const u32* __restrict__ xb, const int* __restrict__ csr,
    const int* __restrict__ cur, const int* __restrict__ deg,
    u32* __restrict__ aggxb) {
  int tid = blockIdx.x * 256 + threadIdx.x;
  int n = tid >> 4, L = tid & 15;
  int i = cur[n];
  int end = i + deg[n];
  float a0 = 0.f, a1 = 0.f, a2 = 0.f, a3 = 0.f;
  float b0 = 0.f, b1 = 0.f, b2 = 0.f, b3 = 0.f;
  for (; i + 1 < end; i += 2) {
    int s0 = csr[i], s1 = csr[i + 1];
    uint2 u = *(const uint2*)&xb[s0 * 32 + 2 * L];
    uint2 w = *(const uint2*)&xb[s1 * 32 + 2 * L];
    a0 += BFLO(u.x); a1 += BFHI(u.x); a2 += BFLO(u.y); a3 += BFHI(u.y);
    b0 += BFLO(w.x); b1 += BFHI(w.x); b2 += BFLO(w.y); b3 += BFHI(w.y);
  }
  if (i < end) {
    int s0 = csr[i];
    uint2 u = *(const uint2*)&xb[s0 * 32 + 2 * L];
    a0 += BFLO(u.x); a1 += BFHI(u.x); a2 += BFLO(u.y); a3 += BFHI(u.y);
  }
  uint2 o;
  o.x = pack_bf16(a0 + b0, a1 + b1);
  o.y = pack_bf16(a2 + b2, a3 + b3);
  *(uint2*)&aggxb[n * 32 + 2 * L] = o;
}

// hb = bf16([aggx | x] @ [Wrel0 ; Wroot0]) (M=NN, K=128, N=128) + BN0 partials.
// MFMA bf16: 128-node tile, 4 waves, wave w owns cols [32w, 32w+32).
// A staged in 32KB XOR-swizzled LDS; both halves read pre-packed bf16
// (aggxb / xb -- identical rounding to previous fp32-x path).
// Output stored bf16 (adjacent-column pairs via shfl_xor(1), the proven
// gemm_b yb pattern): hb[n*64+c2] = pack(h[2c2], h[2c2+1]).
// BN0 stat partials still accumulated from fp32 accs.
__global__ __launch_bounds__(256) void k_gemm_a(
    const u32* __restrict__ xb, const u32* __restrict__ aggxb,
    const u32* __restrict__ Wpk0,
    u32* __restrict__ hb, float* __restrict__ psum, float* __restrict__ pssq) {
  __shared__ u32 As[8192];  // 128 rows x 128 k bf16, XOR-swizzled
  const int tid = threadIdx.x;
  const int nb = blockIdx.x * 128;
  char* AsB = (char*)As;
#pragma unroll
  for (int it = 0; it < 16; ++it) {
    int f = tid + 256 * it;          // 0..4095 over [128 rows][32 u32-pairs]
    int row = f >> 5, k4 = f & 31;   // k = 4*k4 .. 4*k4+3
    int n = nb + row;
    const u32* src = (k4 < 16) ? &aggxb[n * 32 + 2 * k4] : &xb[n * 32 + 2 * (k4 - 16)];
    uint2 p = (n < NN) ? *(const uint2*)src : make_uint2(0u, 0u);
    int byte = row * 256 + k4 * 8;
    byte ^= (row & 7) << 4;
    *(uint2*)(AsB + byte) = p;
  }
  __syncthreads();
  const int lane = tid & 63;
  const int w = tid >> 6;
  const int lr = lane & 15;  // A row-in-tile / D col-in-tile
  const int lg = lane >> 4;  // k-group / D row-group
  f32x4 zero = {0.f, 0.f, 0.f, 0.f};
  f32x4 acc[8][2];
#pragma unroll
  for (int m = 0; m < 8; ++m) {
    acc[m][0] = zero;
    acc[m][1] = zero;
  }
#pragma unroll
  for (int s = 0; s < 4; ++s) {
    s16x8 bf[2];
#pragma unroll
    for (int nt = 0; nt < 2; ++nt)
      bf[nt] = *(const s16x8*)&Wpk0[(((2 * w + nt) * 4 + s) * 64 + lane) * 4];
#pragma unroll
    for (int m = 0; m < 8; ++m) {
      int row = 16 * m + lr;
      int byte = row * 256 + 64 * s + 16 * lg;
      byte ^= (row & 7) << 4;
      s16x8 af = *(const s16x8*)(AsB + byte);
      acc[m][0] = __builtin_amdgcn_mfma_f32_16x16x32_bf16(af, bf[0], acc[m][0], 0, 0, 0);
      acc[m][1] = __builtin_amdgcn_mfma_f32_16x16x32_bf16(af, bf[1], acc[m][1], 0, 0, 0);
    }
  }
  // Epilogue 1: BN0 partials from fp32 accs (C layout: col=lane&15, row=4lg+i).
  float ps[2] = {0.f, 0.f}, qs[2] = {0.f, 0.f};
#pragma unroll
  for (int m = 0; m < 8; ++m) {
#pragma unroll
    for (int nt = 0; nt < 2; ++nt) {
#pragma unroll
      for (int i = 0; i < 4; ++i) {
        float a = acc[m][nt][i];
        ps[nt] += a;
        qs[nt] += a * a;
      }
    }
  }
  // Epilogue 2: bf16 store, adjacent-column pairing via shfl_xor(1).
#pragma unroll
  for (int m = 0; m < 8; ++m) {
    int rowb = nb + 16 * m + 4 * lg;
#pragma unroll
    for (int nt = 0; nt < 2; ++nt) {
      int colg = 32 * w + 16 * nt + lr;
      float a0 = acc[m][nt][0], a1 = acc[m][nt][1];
      float a2 = acc[m][nt][2], a3 = acc[m][nt][3];
      float o0 = __shfl_xor(a0, 1), o1 = __shfl_xor(a1, 1);
      float o2 = __shfl_xor(a2, 1), o3 = __shfl_xor(a3, 1);
      int c2 = colg >> 1;
      u32 q0, q1;
      int i0;
      if ((lane & 1) == 0) {
        q0 = pack_bf16(a0, o0); q1 = pack_bf16(a1, o1); i0 = 0;
      } else {
        q0 = pack_bf16(o2, a2); q1 = pack_bf16(o3, a3); i0 = 2;
      }
      int n0 = rowb + i0, n1 = rowb + i0 + 1;
      if (n0 < NN) hb[n0 * 64 + c2] = q0;
      if (n1 < NN) hb[n1 * 64 + c2] = q1;
    }
  }
  __syncthreads();  // safe LDS reuse
  float* S = (float*)As;   // [4][128]
  float* Q = S + 512;      // [4][128]
#pragma unroll
  for (int nt = 0; nt < 2; ++nt) {
    int colg = 32 * w + 16 * nt + lr;
    S[lg * 128 + colg] = ps[nt];
    Q[lg * 128 + colg] = qs[nt];
  }
  __syncthreads();
  if (tid < 128) {
    float s = 0.f, q = 0.f;
#pragma unroll
    for (int g = 0; g < 4; ++g) { s += S[g * 128 + tid]; q += Q[g * 128 + tid]; }
    psum[blockIdx.x * 128 + tid] = s;
    pssq[blockIdx.x * 128 + tid] = q;
  }
}

// Parallel partial reduction -> scale/shift. 128 blocks (one per channel) x 64 lanes.
__global__ __launch_bounds__(64) void k_bnfin(
    const float* __restrict__ psum, const float* __restrict__ pssq,
    const float* __restrict__ gamma, const float* __restrict__ beta,
    float* __restrict__ scale, float* __restrict__ shift, int P) {
  const int c = blockIdx.x;
  const int t = threadIdx.x;
  float S = 0.f, Q = 0.f;
  for (int p = t; p < P; p += 64) {
    S += psum[p * 128 + c];
    Q += pssq[p * 128 + c];
  }
  for (int off = 32; off > 0; off >>= 1) {
    S += __shfl_down(S, off);
    Q += __shfl_down(Q, off);
  }
  if (t == 0) {
    float mean = S * (1.0f / NN);
    float var = fmaxf(Q * (1.0f / NN) - mean * mean, 0.f);
    float sc = gamma[c] * rsqrtf(var + EPSV);
    scale[c] = sc;
    shift[c] = beta[c] - mean * sc;
  }
}

// t = relu(bn(unpack(hb))); yb = bf16(t @ Wrel1) packed; h = t @ Wroot1 (fp32).
// MFMA bf16: 64-node tile, 4 waves, wave w owns cols [64w, 64w+64).
// Staging now reads bf16 hb (uint2 = 4 adjacent channels) -> bn+relu -> repack.
__global__ __launch_bounds__(256) void k_gemm_b(
    const u32* __restrict__ hb, const u32* __restrict__ Wpk,
    const float* __restrict__ scale, const float* __restrict__ shift,
    u32* __restrict__ yb, float* __restrict__ h) {
  __shared__ u32 As[4096];  // 64 rows x 128 k bf16, XOR-swizzled
  const int tid = threadIdx.x;
  const int nb = blockIdx.x * 64;
  char* AsB = (char*)As;
#pragma unroll
  for (int it = 0; it < 8; ++it) {
    int f = tid + 256 * it;          // 0..2047 over [64 rows][32 uint2]
    int row = f >> 5, k4 = f & 31;   // channels 4*k4 .. 4*k4+3
    int n = nb + row;
    uint2 v = (n < NN) ? *(const uint2*)&hb[n * 64 + 2 * k4] : make_uint2(0u, 0u);
    float4 sc = *(const float4*)&scale[4 * k4];
    float4 sh = *(const float4*)&shift[4 * k4];
    float t0 = fmaxf(BFLO(v.x) * sc.x + sh.x, 0.f);
    float t1 = fmaxf(BFHI(v.x) * sc.y + sh.y, 0.f);
    float t2 = fmaxf(BFLO(v.y) * sc.z + sh.z, 0.f);
    float t3 = fmaxf(BFHI(v.y) * sc.w + sh.w, 0.f);
    uint2 p;
    p.x = pack_bf16(t0, t1);
    p.y = pack_bf16(t2, t3);
    int byte = row * 256 + k4 * 8;
    byte ^= (row & 7) << 4;
    *(uint2*)(AsB + byte) = p;
  }
  __syncthreads();
  const int lane = tid & 63;
  const int w = tid >> 6;
  const int lr = lane & 15;  // A row-in-tile / B,D col-in-tile
  const int lg = lane >> 4;  // k-group
  f32x4 zero = {0.f, 0.f, 0.f, 0.f};
  f32x4 acc[4][4];
#pragma unroll
  for (int m = 0; m < 4; ++m)
#pragma unroll
    for (int nt = 0; nt < 4; ++nt) acc[m][nt] = zero;

#pragma unroll
  for (int s = 0; s < 4; ++s) {
    s16x8 af[4];
#pragma unroll
    for (int m = 0; m < 4; ++m) {
      int row = 16 * m + lr;
      int byte = row * 256 + 64 * s + 16 * lg;
      byte ^= (row & 7) << 4;
      af[m] = *(const s16x8*)(AsB + byte);
    }
    s16x8 bf[4];
#pragma unroll
    for (int nt = 0; nt < 4; ++nt) {
      int gnt = w * 4 + nt;
      bf[nt] = *(const s16x8*)&Wpk[((gnt * 4 + s) * 64 + lane) * 4];
    }
#pragma unroll
    for (int m = 0; m < 4; ++m)
#pragma unroll
      for (int nt = 0; nt < 4; ++nt)
        acc[m][nt] = __builtin_amdgcn_mfma_f32_16x16x32_bf16(
            af[m], bf[nt], acc[m][nt], 0, 0, 0);
  }
  if (w < 2) {  // cols 0..127 -> yb (bf16 pairs)
#pragma unroll
    for (int m = 0; m < 4; ++m) {
#pragma unroll
      for (int nt = 0; nt < 4; ++nt) {
        int colg = 64 * w + 16 * nt + lr;
        int rowb = nb + 16 * m + 4 * lg;
        float a0 = acc[m][nt][0], a1 = acc[m][nt][1];
        float a2 = acc[m][nt][2], a3 = acc[m][nt][3];
        float o0 = __shfl_xor(a0, 1), o1 = __shfl_xor(a1, 1);
        float o2 = __shfl_xor(a2, 1), o3 = __shfl_xor(a3, 1);
        int c2 = colg >> 1;
        u32 q0, q1;
        int i0;
        if ((lane & 1) == 0) {
          q0 = pack_bf16(a0, o0); q1 = pack_bf16(a1, o1); i0 = 0;
        } else {
          q0 = pack_bf16(o2, a2); q1 = pack_bf16(o3, a3); i0 = 2;
        }
        int n0 = rowb + i0, n1 = rowb + i0 + 1;
        if (n0 < NN) yb[n0 * 64 + c2] = q0;
        if (n1 < NN) yb[n1 * 64 + c2] = q1;
      }
    }
  } else {  // cols 128..255 -> h (fp32)
#pragma unroll
    for (int m = 0; m < 4; ++m) {
#pragma unroll
      for (int nt = 0; nt < 4; ++nt) {
        int colg = 64 * (w - 2) + 16 * nt + lr;
        int rowb = nb + 16 * m + 4 * lg;
#pragma unroll
        for (int i = 0; i < 4; ++i) {
          int n = rowb + i;
          if (n < NN) h[n * 128 + colg] = acc[m][nt][i];
        }
      }
    }
  }
}

// h[n] += sum over incoming edges of unpack(yb[src]) + fused BN1 stat partials.
__global__ __launch_bounds__(256) void k_gather2(
    const u32* __restrict__ yb, const int* __restrict__ csr,
    const int* __restrict__ cur, const int* __restrict__ deg,
    float* __restrict__ h, float* __restrict__ psum, float* __restrict__ pssq) {
  int tid = blockIdx.x * 256 + threadIdx.x;
  int n = tid >> 4;
  int L = threadIdx.x & 15;
  int base = L << 2;   // u32 index within yb row
  int c0 = L << 3;     // first channel handled by this lane
  int i = cur[n];
  int end = i + deg[n];
  float lo0 = 0.f, lo1 = 0.f, lo2 = 0.f, lo3 = 0.f;
  float hi0 = 0.f, hi1 = 0.f, hi2 = 0.f, hi3 = 0.f;
  float mo0 = 0.f, mo1 = 0.f, mo2 = 0.f, mo3 = 0.f;
  float ni0 = 0.f, ni1 = 0.f, ni2 = 0.f, ni3 = 0.f;
  for (; i + 1 < end; i += 2) {
    int s0 = csr[i], s1 = csr[i + 1];
    uint4 v = *(const uint4*)&yb[s0 * 64 + base];
    uint4 w = *(const uint4*)&yb[s1 * 64 + base];
    lo0 += BFLO(v.x); hi0 += BFHI(v.x);
    lo1 += BFLO(v.y); hi1 += BFHI(v.y);
    lo2 += BFLO(v.z); hi2 += BFHI(v.z);
    lo3 += BFLO(v.w); hi3 += BFHI(v.w);
    mo0 += BFLO(w.x); ni0 += BFHI(w.x);
    mo1 += BFLO(w.y); ni1 += BFHI(w.y);
    mo2 += BFLO(w.z); ni2 += BFHI(w.z);
    mo3 += BFLO(w.w); ni3 += BFHI(w.w);
  }
  if (i < end) {
    int s = csr[i];
    uint4 v = *(const uint4*)&yb[s * 64 + base];
    lo0 += BFLO(v.x); hi0 += BFHI(v.x);
    lo1 += BFLO(v.y); hi1 += BFHI(v.y);
    lo2 += BFLO(v.z); hi2 += BFHI(v.z);
    lo3 += BFLO(v.w); hi3 += BFHI(v.w);
  }
  // channels: c0+0: lo0   c0+1: hi0   c0+2: lo1   c0+3: hi1
  //           c0+4: lo2   c0+5: hi2   c0+6: lo3   c0+7: hi3
  float4 A = *(const float4*)&h[n * 128 + c0];
  float4 B = *(const float4*)&h[n * 128 + c0 + 4];
  float4 R0 = make_float4(A.x + lo0 + mo0, A.y + hi0 + ni0,
                          A.z + lo1 + mo1, A.w + hi1 + ni1);
  float4 R1 = make_float4(B.x + lo2 + mo2, B.y + hi2 + ni2,
                          B.z + lo3 + mo3, B.w + hi3 + ni3);
  *(float4*)&h[n * 128 + c0]     = R0;
  *(float4*)&h[n * 128 + c0 + 4] = R1;
  // Fused BN1 stat partials: block covers 16 nodes x 128 channels.
  __shared__ float S[16 * 132], Q[16 * 132];
  const int nl = threadIdx.x >> 4;
  *(float4*)&S[nl * 132 + c0]     = R0;
  *(float4*)&S[nl * 132 + c0 + 4] = R1;
  *(float4*)&Q[nl * 132 + c0] =
      make_float4(R0.x * R0.x, R0.y * R0.y, R0.z * R0.z, R0.w * R0.w);
  *(float4*)&Q[nl * 132 + c0 + 4] =
      make_float4(R1.x * R1.x, R1.y * R1.y, R1.z * R1.z, R1.w * R1.w);
  __syncthreads();
  const int t = threadIdx.x;
  if (t < 128) {
    float s = 0.f, q = 0.f;
#pragma unroll
    for (int g = 0; g < 16; ++g) { s += S[g * 132 + t]; q += Q[g * 132 + t]; }
    psum[blockIdx.x * 128 + t] = s;
    pssq[blockIdx.x * 128 + t] = q;
  }
}

__global__ __launch_bounds__(256) void k_final(
    const float* __restrict__ h, const float* __restrict__ scale,
    const float* __restrict__ shift, float* __restrict__ out) {
  int tid = blockIdx.x * 256 + threadIdx.x;
  int base = tid << 2;
  int f4 = base & 127;
  float4 v = *(const float4*)&h[base];
  float4 sc = *(const float4*)&scale[f4];
  float4 sh = *(const float4*)&shift[f4];
  *(float4*)&out[base] = make_float4(v.x * sc.x + sh.x, v.y * sc.y + sh.y,
                                     v.z * sc.z + sh.z, v.w * sc.w + sh.w);
}

extern "C" void kernel_launch(void* const* d_in, const int* in_sizes, int n_in,
                              void* d_out, int out_size, void* d_ws, size_t ws_size,
                              hipStream_t stream) {
  if (ws_size < WS_NEEDED) {
    k_fallback<<<(NN * 128 + 255) / 256, 256, 0, stream>>>((float*)d_out);
    return;
  }
  const float* x      = (const float*)d_in[0];
  const int*   ei     = (const int*)d_in[1];
  const float* Wrel0  = (const float*)d_in[2];
  // d_in[3] = b_rel0: per-channel constant pre-BN -> cancels in BN, unused
  const float* Wroot0 = (const float*)d_in[4];
  const float* gamma0 = (const float*)d_in[5];
  const float* beta0  = (const float*)d_in[6];
  const float* Wrel1  = (const float*)d_in[7];
  // d_in[8] = b_rel1: unused (cancels in BN)
  const float* Wroot1 = (const float*)d_in[9];
  const float* gamma1 = (const float*)d_in[10];
  const float* beta1  = (const float*)d_in[11];

  u32*   aggxb = (u32*)d_ws;             // NN*32 u32 (region holds yb NN*64 later)
  u32*   yb   = (u32*)d_ws;              // NN*64 u32 (after gemm_a)
  u32*   xb   = (u32*)((float*)d_ws + NN * 64);  // NN*32, live through gemm_a
  float* st   = (float*)(xb + NN * 32);  // 1024 floats
  float* scale0 = st;       float* shift0 = st + 128;
  float* scale1 = st + 256; float* shift1 = st + 384;
  int* mode = (int*)(st + 512);
  int* bsum = (int*)(st + 576);          // 196 ints
  int* deg = (int*)(st + 1024);          // NN
  int* cur = deg + NN;                   // NN
  int* csr = cur + NN;                   // NE
  float* psum = (float*)(csr + NE);      // 400000 (3125*128)
  float* pssq = psum + 400000;           // 400000
  int* rank = (int*)psum;                // NE ints (spans psum+pssq); dead later
  u32* pedge = (u32*)(pssq + 400000);    // NE packed edges (src<<16|dst)
  u32* Wpk  = pedge + NE;                // 16384 u32, layer-1 B frags
  u32* Wpk0 = Wpk + 16384;               // 8192 u32, layer-0 B frags
  u32* hb   = Wpk0 + 8192;               // NN*64 u32, bf16 layer-0 h
  float* h = (float*)d_out;              // layer-1 h lives in d_out; k_final in-place

  hipMemsetAsync(deg, 0, (size_t)NN * 4, stream);
  k_detect<<<1, 64, 0, stream>>>(ei, mode);
  k_hist<<<NE / 256, 256, 0, stream>>>(ei, mode, deg, rank, pedge);
  k_scan1<<<196, 256, 0, stream>>>(deg, bsum);
  k_scan3<<<196, 256, 0, stream>>>(deg, bsum, cur);
  k_place<<<NE / 256, 256, 0, stream>>>(pedge, cur, rank, csr);

  k_prep<<<6346, 256, 0, stream>>>(x, xb, Wrel1, Wroot1, Wpk, Wrel0, Wroot0, Wpk0);
  k_gather_xb<<<(NN * 16) / 256, 256, 0, stream>>>(xb, csr, cur, deg, aggxb);
  k_gemm_a<<<(NN + 127) / 128, 256, 0, stream>>>(xb, aggxb, Wpk0, hb, psum, pssq);
  k_bnfin<<<128, 64, 0, stream>>>(psum, pssq, gamma0, beta0, scale0, shift0, 391);
  k_gemm_b<<<(NN + 63) / 64, 256, 0, stream>>>(hb, Wpk, scale0, shift0, yb, h);
  k_gather2<<<(NN * 16) / 256, 256, 0, stream>>>(yb, csr, cur, deg, h, psum, pssq);
  k_bnfin<<<128, 64, 0, stream>>>(psum, pssq, gamma1, beta1, scale1, shift1, 3125);
  k_final<<<(NN * 128) / 1024, 256, 0, stream>>>(h, scale1, shift1, (float*)d_out);
}